// Round 5
// baseline (1673.762 us; speedup 1.0000x reference)
//
#include <hip/hip_runtime.h>
#include <cstddef>

#define NROWS 16384
#define NE    8192
#define DD    256
#define TM    256
#define TN    128
#define BK    32
#define NCH   8
#define CHW   (NE / NCH)   // 1024 cols per chunk

typedef unsigned long long u64;
typedef float vf4 __attribute__((ext_vector_type(4)));

// ---------------------------------------------------------------------------
// k_rowsq: zsq[n] = sum(z[n,:]^2) in numpy pairwise order (256 = 128+128,
// each 128-block via 8 strided accumulators). esq likewise. Also inits
// best[] to u64-max, zeroes counts + loss accumulator.
// ---------------------------------------------------------------------------
__global__ __launch_bounds__(256) void k_rowsq(
    const float* __restrict__ z, const float* __restrict__ emb,
    float* __restrict__ zsq, float* __restrict__ esq,
    u64* __restrict__ best, int* __restrict__ counts,
    float* __restrict__ loss_acc)
{
  const int g = blockIdx.x * 256 + threadIdx.x;   // 0 .. 24575
  if (g < NE) counts[g] = 0;
  if (g < NROWS) best[g] = ~0ull;
  if (g == 0) *loss_acc = 0.0f;

  const float* row;
  float* outp;
  if (g < NROWS) { row = z + (size_t)g * DD;            outp = zsq + g; }
  else           { row = emb + (size_t)(g - NROWS) * DD; outp = esq + (g - NROWS); }

  float half_s[2];
#pragma unroll
  for (int h = 0; h < 2; ++h) {
    const float* p = row + h * 128;
    float r[8];
#pragma unroll
    for (int j = 0; j < 8; ++j) {
      float x = p[j];
      float sq = x * x;
      asm volatile("" : "+v"(sq));   // block FMA contraction: np rounds x*x first
      r[j] = sq;
    }
    for (int i = 8; i < 128; i += 8) {
#pragma unroll
      for (int j = 0; j < 8; ++j) {
        float x = p[i + j];
        float sq = x * x;
        asm volatile("" : "+v"(sq));
        r[j] = r[j] + sq;
      }
    }
    half_s[h] = ((r[0] + r[1]) + (r[2] + r[3])) + ((r[4] + r[5]) + (r[6] + r[7]));
  }
  *outp = half_s[0] + half_s[1];
}

// ---------------------------------------------------------------------------
// k_argmin v4: 256x128 block tile, 256 threads, 16x8 micro-tile.
// Round-4 lesson: __launch_bounds__(256,2) + unroll 8 made the allocator
// settle at 128 VGPRs and spill the 128-float acc tile (WRITE_SIZE 89 MB).
// Fix: pin occupancy to exactly 2 waves/EU (256-VGPR budget), unroll kk by 2
// so only ~2x24 operand regs are live, and keep zr loads out of the kk loop.
// Accumulation: sequential k, FMA — bit-identical to rounds 1/3/4.
// Cross-block reduce via atomicMin on packed (float_bits(d)<<32)|col.
// ---------------------------------------------------------------------------
__global__ __launch_bounds__(256)
__attribute__((amdgpu_waves_per_eu(2, 2)))
void k_argmin(
    const float* __restrict__ z, const float* __restrict__ emb,
    const float* __restrict__ zsq, const float* __restrict__ esq,
    u64* __restrict__ best)
{
  __shared__ float As[BK][TM];          // 32 KB
  __shared__ float Bs[BK][TN];          // 16 KB

  const int tid = threadIdx.x;
  const int tx = tid & 15;
  const int ty = tid >> 4;
  const int tx4 = tx * 4;
  const int ty4 = ty * 4;
  const int R0 = blockIdx.x * TM;
  const int C0 = blockIdx.y * CHW;

  const int bcol  = tid & 127;          // B staging col
  const int bkoff = (tid >> 7) * 16;    // B staging k-half

  u64 bp[16];
#pragma unroll
  for (int i = 0; i < 16; ++i) bp[i] = ~0ull;

  for (int t = 0; t < CHW; t += TN) {
    const int Cb = C0 + t;
    float acc[16][8];
#pragma unroll
    for (int i = 0; i < 16; ++i)
#pragma unroll
      for (int j = 0; j < 8; ++j) acc[i][j] = 0.0f;

    for (int k0 = 0; k0 < DD; k0 += BK) {
      __syncthreads();
      // A: each thread stages its own row's 32-k slice (row = R0+tid)
#pragma unroll
      for (int q = 0; q < 8; ++q) {
        const float4 v = *(const float4*)(z + (size_t)(R0 + tid) * DD + k0 + 4 * q);
        As[4 * q + 0][tid] = v.x;
        As[4 * q + 1][tid] = v.y;
        As[4 * q + 2][tid] = v.z;
        As[4 * q + 3][tid] = v.w;
      }
      // B: 128 cols x 32 k, two thread-halves take k-halves
#pragma unroll
      for (int q = 0; q < 4; ++q) {
        const float4 v = *(const float4*)(emb + (size_t)(Cb + bcol) * DD + k0 + bkoff + 4 * q);
        Bs[bkoff + 4 * q + 0][bcol] = v.x;
        Bs[bkoff + 4 * q + 1][bcol] = v.y;
        Bs[bkoff + 4 * q + 2][bcol] = v.z;
        Bs[bkoff + 4 * q + 3][bcol] = v.w;
      }
      __syncthreads();
#pragma unroll 2
      for (int kk = 0; kk < BK; ++kk) {
        const float4 a0 = *(const float4*)(&As[kk][ty4]);
        const float4 a1 = *(const float4*)(&As[kk][ty4 + 64]);
        const float4 a2 = *(const float4*)(&As[kk][ty4 + 128]);
        const float4 a3 = *(const float4*)(&As[kk][ty4 + 192]);
        const float4 b0 = *(const float4*)(&Bs[kk][tx4]);
        const float4 b1 = *(const float4*)(&Bs[kk][tx4 + 64]);
        const float av[16] = {a0.x, a0.y, a0.z, a0.w, a1.x, a1.y, a1.z, a1.w,
                              a2.x, a2.y, a2.z, a2.w, a3.x, a3.y, a3.z, a3.w};
        const float bv[8]  = {b0.x, b0.y, b0.z, b0.w, b1.x, b1.y, b1.z, b1.w};
#pragma unroll
        for (int i = 0; i < 16; ++i)
#pragma unroll
          for (int j = 0; j < 8; ++j)
            acc[i][j] += av[i] * bv[j];
      }
    }

#pragma unroll
    for (int j = 0; j < 8; ++j) {
      const int col = Cb + tx4 + ((j < 4) ? j : 64 + j - 4);
      const float ev = esq[col];
#pragma unroll
      for (int i = 0; i < 16; ++i) {
        const float zri = zsq[R0 + (i >> 2) * 64 + ty4 + (i & 3)];
        const float s1 = zri + ev;                // fl(zsq+esq), matches np
        const float dv = s1 - 2.0f * acc[i][j];   // fl(s1 - 2*dot); 2*dot exact
        const u64 p = ((u64)__float_as_uint(dv) << 32) | (unsigned)col;
        if (p < bp[i]) bp[i] = p;
      }
    }
  }

  // reduce across the 16 tx lanes (contiguous 16-lane groups share ty)
#pragma unroll
  for (int i = 0; i < 16; ++i) {
#pragma unroll
    for (int off = 8; off > 0; off >>= 1) {
      const u64 o = __shfl_xor(bp[i], off, 16);
      if (o < bp[i]) bp[i] = o;
    }
  }
  if (tx == 0) {
#pragma unroll
    for (int i = 0; i < 16; ++i) {
      const int r = R0 + (i >> 2) * 64 + ty4 + (i & 3);
      atomicMin(&best[r], bp[i]);
    }
  }
}

// ---------------------------------------------------------------------------
// k_zero: zero the 537 MB one-hot region with nontemporal (L2-bypassing)
// stores. Base is only 8B-aligned (out + 4194306): 2-float head/tail, vf4
// middle.
// ---------------------------------------------------------------------------
#define OH_TOT   ((size_t)NROWS * NE)            // 134217728 floats
#define OH_VEC   ((OH_TOT - 4) / 4)              // 33554431 vf4 stores
__global__ __launch_bounds__(256) void k_zero(float* __restrict__ base)
{
  const size_t i0 = (size_t)blockIdx.x * 256 + threadIdx.x;
  const size_t stride = (size_t)gridDim.x * 256;
  vf4 zero = {0.0f, 0.0f, 0.0f, 0.0f};
  float* p = base + 2;                           // 16B-aligned
  for (size_t t = i0; t < OH_VEC; t += stride)
    __builtin_nontemporal_store(zero, (vf4*)(p + 4 * t));
  if (i0 == 0) {
    base[0] = 0.0f; base[1] = 0.0f;
    base[OH_TOT - 2] = 0.0f; base[OH_TOT - 1] = 0.0f;
  }
}

// ---------------------------------------------------------------------------
// k_scatter: one 64-lane group per row. Gathers z_q, writes the one-hot 1.0,
// float(index), loss partials, counts.
// ---------------------------------------------------------------------------
__global__ __launch_bounds__(256) void k_scatter(
    const float* __restrict__ z, const float* __restrict__ emb,
    const u64* __restrict__ best,
    float* __restrict__ out_zq, float* __restrict__ out_onehot,
    float* __restrict__ out_idx, float* __restrict__ loss_acc,
    int* __restrict__ counts)
{
  const int row = blockIdx.x * 4 + (threadIdx.x >> 6);
  const int lane = threadIdx.x & 63;
  const int idx = (int)(unsigned)(best[row] & 0xffffffffull);
  const int k0 = lane * 4;

  const float4 e  = *(const float4*)(emb + (size_t)idx * DD + k0);
  const float4 zv = *(const float4*)(z + (size_t)row * DD + k0);
  *(float4*)(out_zq + (size_t)row * DD + k0) = e;

  const float dx = e.x - zv.x, dy = e.y - zv.y, dz = e.z - zv.z, dw = e.w - zv.w;
  float local = dx * dx + dy * dy + dz * dz + dw * dw;
#pragma unroll
  for (int off = 32; off > 0; off >>= 1) local += __shfl_down(local, off, 64);
  if (lane == 0) {
    atomicAdd(loss_acc, local);
    out_idx[row] = (float)idx;
    out_onehot[(size_t)row * NE + idx] = 1.0f;
    atomicAdd(&counts[idx], 1);
  }
}

// ---------------------------------------------------------------------------
// k_final: perplexity = exp(-sum(p*log(p+1e-10))), loss = 1.25 * mean.
// ---------------------------------------------------------------------------
__global__ __launch_bounds__(256) void k_final(
    const int* __restrict__ counts, const float* __restrict__ loss_acc,
    float* __restrict__ out_loss, float* __restrict__ out_perp)
{
  __shared__ float sred[256];
  float local = 0.0f;
  for (int e = threadIdx.x; e < NE; e += 256) {
    const float p = (float)counts[e] * (1.0f / 16384.0f);
    local += p * logf(p + 1e-10f);
  }
  sred[threadIdx.x] = local;
  __syncthreads();
  for (int s = 128; s > 0; s >>= 1) {
    if (threadIdx.x < s) sred[threadIdx.x] += sred[threadIdx.x + s];
    __syncthreads();
  }
  if (threadIdx.x == 0) {
    *out_perp = expf(-sred[0]);
    *out_loss = *loss_acc * (1.25f / 4194304.0f);  // (1+beta) * sum / (N*D)
  }
}

// ---------------------------------------------------------------------------
// Output layout (float32, concatenated in reference return order):
//   [0]                loss                       (1)
//   [1 .. 4194304]     z_q_st                     (16384*256)
//   [4194305]          perplexity                 (1)
//   [4194306 ..]       min_encodings one-hot      (16384*8192)
//   [138412034 ..]     min_encoding_indices       (16384, written as float)
// ---------------------------------------------------------------------------
extern "C" void kernel_launch(void* const* d_in, const int* in_sizes, int n_in,
                              void* d_out, int out_size, void* d_ws, size_t ws_size,
                              hipStream_t stream) {
  const float* z   = (const float*)d_in[0];
  const float* emb = (const float*)d_in[1];

  float* out        = (float*)d_out;
  float* out_loss   = out;
  float* out_zq     = out + 1;
  float* out_perp   = out + 4194305;
  float* out_onehot = out + 4194306;
  float* out_idx    = out + 138412034;

  float* zsq      = (float*)d_ws;            // 16384 f
  float* esq      = zsq + NROWS;             // 8192 f
  u64*   best     = (u64*)(esq + NE);        // 16384 u64 (8B-aligned: offset 96 KB)
  int*   counts   = (int*)(best + NROWS);    // 8192 int
  float* loss_acc = (float*)(counts + NE);   // 1 f

  k_zero<<<4096, 256, 0, stream>>>(out_onehot);
  k_rowsq<<<96, 256, 0, stream>>>(z, emb, zsq, esq, best, counts, loss_acc);
  k_argmin<<<dim3(NROWS / TM, NCH), 256, 0, stream>>>(z, emb, zsq, esq, best);
  k_scatter<<<NROWS / 4, 256, 0, stream>>>(z, emb, best, out_zq, out_onehot,
                                           out_idx, loss_acc, counts);
  k_final<<<1, 256, 0, stream>>>(counts, loss_acc, out_loss, out_perp);
}

// Round 6
// 1573.929 us; speedup vs baseline: 1.0634x; 1.0634x over previous
//
#include <hip/hip_runtime.h>
#include <cstddef>

#define NROWS 16384
#define NE    8192
#define DD    256
#define TM    256
#define TN    128
#define BK    16
#define NCH   8
#define CHW   (NE / NCH)   // 1024 cols per chunk

typedef unsigned long long u64;

// ---------------------------------------------------------------------------
// k_rowsq: zsq[n] = sum(z[n,:]^2) in numpy pairwise order (256 = 128+128,
// each 128-block via 8 strided accumulators r[j] += x[8i+j]^2, combined
// pairwise). float4 loads (same add order as scalar). Also inits best[],
// counts, loss accumulator.
// ---------------------------------------------------------------------------
__global__ __launch_bounds__(256) void k_rowsq(
    const float* __restrict__ z, const float* __restrict__ emb,
    float* __restrict__ zsq, float* __restrict__ esq,
    u64* __restrict__ best, int* __restrict__ counts,
    float* __restrict__ loss_acc)
{
  const int g = blockIdx.x * 256 + threadIdx.x;   // 0 .. 24575
  if (g < NE) counts[g] = 0;
  if (g < NROWS) best[g] = ~0ull;
  if (g == 0) *loss_acc = 0.0f;

  const float* row;
  float* outp;
  if (g < NROWS) { row = z + (size_t)g * DD;            outp = zsq + g; }
  else           { row = emb + (size_t)(g - NROWS) * DD; outp = esq + (g - NROWS); }

  float half_s[2];
#pragma unroll
  for (int h = 0; h < 2; ++h) {
    const float* p = row + h * 128;
    float r[8];
    {
      const float4 v0 = *(const float4*)(p);
      const float4 v1 = *(const float4*)(p + 4);
      const float xs[8] = {v0.x, v0.y, v0.z, v0.w, v1.x, v1.y, v1.z, v1.w};
#pragma unroll
      for (int j = 0; j < 8; ++j) {
        float sq = xs[j] * xs[j];
        asm volatile("" : "+v"(sq));   // block FMA contraction: np rounds x*x first
        r[j] = sq;
      }
    }
    for (int i = 8; i < 128; i += 8) {
      const float4 v0 = *(const float4*)(p + i);
      const float4 v1 = *(const float4*)(p + i + 4);
      const float xs[8] = {v0.x, v0.y, v0.z, v0.w, v1.x, v1.y, v1.z, v1.w};
#pragma unroll
      for (int j = 0; j < 8; ++j) {
        float sq = xs[j] * xs[j];
        asm volatile("" : "+v"(sq));
        r[j] = r[j] + sq;
      }
    }
    half_s[h] = ((r[0] + r[1]) + (r[2] + r[3])) + ((r[4] + r[5]) + (r[6] + r[7]));
  }
  *outp = half_s[0] + half_s[1];
}

// ---------------------------------------------------------------------------
// k_argmin v5: 256x128 block tile, 256 threads, 16x8 micro-tile,
// double-buffered LDS with BK=16: stage chunk k+1 while computing chunk k,
// one barrier per chunk — overlaps global-load latency + ds_writes with the
// FMA stream (round-5 counters: 33% VALU idle = staging/barrier stalls).
// Accumulation: sequential k, FMA — bit-identical to rounds 1-5.
// Cross-block reduce via atomicMin on packed (float_bits(d)<<32)|col
// (d>0 so float bits are order-preserving; lowest index wins ties = np).
// ---------------------------------------------------------------------------
__global__ __launch_bounds__(256)
__attribute__((amdgpu_waves_per_eu(2, 2)))
void k_argmin(
    const float* __restrict__ z, const float* __restrict__ emb,
    const float* __restrict__ zsq, const float* __restrict__ esq,
    u64* __restrict__ best)
{
  __shared__ float As[2][BK][TM];       // 32 KB
  __shared__ float Bs[2][BK][TN];       // 16 KB

  const int tid = threadIdx.x;
  const int tx = tid & 15;
  const int ty = tid >> 4;
  const int tx4 = tx * 4;
  const int ty4 = ty * 4;
  const int R0 = blockIdx.x * TM;
  const int C0 = blockIdx.y * CHW;

  const int bcol = tid & 127;           // B staging col
  const int bk8  = (tid >> 7) * 8;      // B staging k-offset (0 or 8)

  const float* zrow = z + (size_t)(R0 + tid) * DD;

  u64 bp[16];
#pragma unroll
  for (int i = 0; i < 16; ++i) bp[i] = ~0ull;

#define STAGE(B_, K_)                                                     \
  {                                                                       \
    _Pragma("unroll")                                                     \
    for (int q = 0; q < 4; ++q) {                                         \
      const float4 v = *(const float4*)(zrow + (K_) + 4 * q);             \
      As[B_][4 * q + 0][tid] = v.x;                                       \
      As[B_][4 * q + 1][tid] = v.y;                                       \
      As[B_][4 * q + 2][tid] = v.z;                                       \
      As[B_][4 * q + 3][tid] = v.w;                                       \
    }                                                                     \
    _Pragma("unroll")                                                     \
    for (int h = 0; h < 2; ++h) {                                         \
      const float4 v = *(const float4*)(ecol + (K_) + 4 * h);             \
      Bs[B_][bk8 + 4 * h + 0][bcol] = v.x;                                \
      Bs[B_][bk8 + 4 * h + 1][bcol] = v.y;                                \
      Bs[B_][bk8 + 4 * h + 2][bcol] = v.z;                                \
      Bs[B_][bk8 + 4 * h + 3][bcol] = v.w;                                \
    }                                                                     \
  }

#define COMPUTE(B_)                                                       \
  _Pragma("unroll 2")                                                     \
  for (int kk = 0; kk < BK; ++kk) {                                       \
    const float4 a0 = *(const float4*)(&As[B_][kk][ty4]);                 \
    const float4 a1 = *(const float4*)(&As[B_][kk][ty4 + 64]);            \
    const float4 a2 = *(const float4*)(&As[B_][kk][ty4 + 128]);           \
    const float4 a3 = *(const float4*)(&As[B_][kk][ty4 + 192]);           \
    const float4 b0 = *(const float4*)(&Bs[B_][kk][tx4]);                 \
    const float4 b1 = *(const float4*)(&Bs[B_][kk][tx4 + 64]);            \
    const float av[16] = {a0.x, a0.y, a0.z, a0.w, a1.x, a1.y, a1.z, a1.w, \
                          a2.x, a2.y, a2.z, a2.w, a3.x, a3.y, a3.z, a3.w};\
    const float bv[8]  = {b0.x, b0.y, b0.z, b0.w, b1.x, b1.y, b1.z, b1.w};\
    _Pragma("unroll")                                                     \
    for (int i = 0; i < 16; ++i)                                          \
      _Pragma("unroll")                                                   \
      for (int j = 0; j < 8; ++j)                                         \
        acc[i][j] += av[i] * bv[j];                                       \
  }

  for (int t = 0; t < CHW; t += TN) {
    const int Cb = C0 + t;
    const float* ecol = emb + (size_t)(Cb + bcol) * DD + bk8;

    float acc[16][8];
#pragma unroll
    for (int i = 0; i < 16; ++i)
#pragma unroll
      for (int j = 0; j < 8; ++j) acc[i][j] = 0.0f;

    STAGE(0, 0);
    __syncthreads();
    for (int c = 0; c < 16; c += 2) {
      if (c + 1 < 16) STAGE(1, (c + 1) * BK);
      COMPUTE(0);
      __syncthreads();
      if (c + 2 < 16) STAGE(0, (c + 2) * BK);
      COMPUTE(1);
      __syncthreads();
    }

#pragma unroll
    for (int j = 0; j < 8; ++j) {
      const int col = Cb + tx4 + ((j < 4) ? j : 64 + j - 4);
      const float ev = esq[col];
#pragma unroll
      for (int i = 0; i < 16; ++i) {
        const float zri = zsq[R0 + (i >> 2) * 64 + ty4 + (i & 3)];
        const float s1 = zri + ev;                // fl(zsq+esq), matches np
        const float dv = s1 - 2.0f * acc[i][j];   // fl(s1 - 2*dot); 2*dot exact
        const u64 p = ((u64)__float_as_uint(dv) << 32) | (unsigned)col;
        if (p < bp[i]) bp[i] = p;
      }
    }
  }

  // reduce across the 16 tx lanes (contiguous 16-lane groups share ty)
#pragma unroll
  for (int i = 0; i < 16; ++i) {
#pragma unroll
    for (int off = 8; off > 0; off >>= 1) {
      const u64 o = __shfl_xor(bp[i], off, 16);
      if (o < bp[i]) bp[i] = o;
    }
  }
  if (tx == 0) {
#pragma unroll
    for (int i = 0; i < 16; ++i) {
      const int r = R0 + (i >> 2) * 64 + ty4 + (i & 3);
      atomicMin(&best[r], bp[i]);
    }
  }
}

// ---------------------------------------------------------------------------
// k_scatter: one 64-lane group per row. Gathers z_q, writes the one-hot 1.0
// (zeros come from hipMemsetAsync), float(index), loss partials, counts.
// ---------------------------------------------------------------------------
__global__ __launch_bounds__(256) void k_scatter(
    const float* __restrict__ z, const float* __restrict__ emb,
    const u64* __restrict__ best,
    float* __restrict__ out_zq, float* __restrict__ out_onehot,
    float* __restrict__ out_idx, float* __restrict__ loss_acc,
    int* __restrict__ counts)
{
  const int row = blockIdx.x * 4 + (threadIdx.x >> 6);
  const int lane = threadIdx.x & 63;
  const int idx = (int)(unsigned)(best[row] & 0xffffffffull);
  const int k0 = lane * 4;

  const float4 e  = *(const float4*)(emb + (size_t)idx * DD + k0);
  const float4 zv = *(const float4*)(z + (size_t)row * DD + k0);
  *(float4*)(out_zq + (size_t)row * DD + k0) = e;

  const float dx = e.x - zv.x, dy = e.y - zv.y, dz = e.z - zv.z, dw = e.w - zv.w;
  float local = dx * dx + dy * dy + dz * dz + dw * dw;
#pragma unroll
  for (int off = 32; off > 0; off >>= 1) local += __shfl_down(local, off, 64);
  if (lane == 0) {
    atomicAdd(loss_acc, local);
    out_idx[row] = (float)idx;
    out_onehot[(size_t)row * NE + idx] = 1.0f;
    atomicAdd(&counts[idx], 1);
  }
}

// ---------------------------------------------------------------------------
// k_final: perplexity = exp(-sum(p*log(p+1e-10))), loss = 1.25 * mean.
// ---------------------------------------------------------------------------
__global__ __launch_bounds__(256) void k_final(
    const int* __restrict__ counts, const float* __restrict__ loss_acc,
    float* __restrict__ out_loss, float* __restrict__ out_perp)
{
  __shared__ float sred[256];
  float local = 0.0f;
  for (int e = threadIdx.x; e < NE; e += 256) {
    const float p = (float)counts[e] * (1.0f / 16384.0f);
    local += p * logf(p + 1e-10f);
  }
  sred[threadIdx.x] = local;
  __syncthreads();
  for (int s = 128; s > 0; s >>= 1) {
    if (threadIdx.x < s) sred[threadIdx.x] += sred[threadIdx.x + s];
    __syncthreads();
  }
  if (threadIdx.x == 0) {
    *out_perp = expf(-sred[0]);
    *out_loss = *loss_acc * (1.25f / 4194304.0f);  // (1+beta) * sum / (N*D)
  }
}

// ---------------------------------------------------------------------------
// Output layout (float32, concatenated in reference return order):
//   [0]                loss                       (1)
//   [1 .. 4194304]     z_q_st                     (16384*256)
//   [4194305]          perplexity                 (1)
//   [4194306 ..]       min_encodings one-hot      (16384*8192)
//   [138412034 ..]     min_encoding_indices       (16384, written as float)
// ---------------------------------------------------------------------------
extern "C" void kernel_launch(void* const* d_in, const int* in_sizes, int n_in,
                              void* d_out, int out_size, void* d_ws, size_t ws_size,
                              hipStream_t stream) {
  const float* z   = (const float*)d_in[0];
  const float* emb = (const float*)d_in[1];

  float* out        = (float*)d_out;
  float* out_loss   = out;
  float* out_zq     = out + 1;
  float* out_perp   = out + 4194305;
  float* out_onehot = out + 4194306;
  float* out_idx    = out + 138412034;

  float* zsq      = (float*)d_ws;            // 16384 f
  float* esq      = zsq + NROWS;             // 8192 f
  u64*   best     = (u64*)(esq + NE);        // 16384 u64 (8B-aligned: offset 96 KB)
  int*   counts   = (int*)(best + NROWS);    // 8192 int
  float* loss_acc = (float*)(counts + NE);   // 1 f

  // driver memset for the 537 MB one-hot zeros (fastest measured path, R1)
  hipMemsetAsync(out_onehot, 0, (size_t)NROWS * NE * sizeof(float), stream);

  k_rowsq<<<96, 256, 0, stream>>>(z, emb, zsq, esq, best, counts, loss_acc);
  k_argmin<<<dim3(NROWS / TM, NCH), 256, 0, stream>>>(z, emb, zsq, esq, best);
  k_scatter<<<NROWS / 4, 256, 0, stream>>>(z, emb, best, out_zq, out_onehot,
                                           out_idx, loss_acc, counts);
  k_final<<<1, 256, 0, stream>>>(counts, loss_acc, out_loss, out_perp);
}

// Round 7
// 1395.052 us; speedup vs baseline: 1.1998x; 1.1282x over previous
//
#include <hip/hip_runtime.h>
#include <cstddef>

#define NROWS 16384
#define NE    8192
#define DD    256
#define TM    256
#define TN    128
#define BK    16
#define NCH   8
#define CHW   (NE / NCH)   // 1024 cols per chunk

typedef unsigned long long u64;
typedef float vf4 __attribute__((ext_vector_type(4)));

// ---------------------------------------------------------------------------
// k_rowsq: zsq[n] = sum(z[n,:]^2) in numpy pairwise order (256 = 128+128,
// each 128-block via 8 strided accumulators r[j] += x[8i+j]^2, combined
// pairwise). float4 loads (same add order as scalar). Also inits best[],
// counts.
// ---------------------------------------------------------------------------
__global__ __launch_bounds__(256) void k_rowsq(
    const float* __restrict__ z, const float* __restrict__ emb,
    float* __restrict__ zsq, float* __restrict__ esq,
    u64* __restrict__ best, int* __restrict__ counts)
{
  const int g = blockIdx.x * 256 + threadIdx.x;   // 0 .. 24575
  if (g < NE) counts[g] = 0;
  if (g < NROWS) best[g] = ~0ull;

  const float* row;
  float* outp;
  if (g < NROWS) { row = z + (size_t)g * DD;            outp = zsq + g; }
  else           { row = emb + (size_t)(g - NROWS) * DD; outp = esq + (g - NROWS); }

  float half_s[2];
#pragma unroll
  for (int h = 0; h < 2; ++h) {
    const float* p = row + h * 128;
    float r[8];
    {
      const float4 v0 = *(const float4*)(p);
      const float4 v1 = *(const float4*)(p + 4);
      const float xs[8] = {v0.x, v0.y, v0.z, v0.w, v1.x, v1.y, v1.z, v1.w};
#pragma unroll
      for (int j = 0; j < 8; ++j) {
        float sq = xs[j] * xs[j];
        asm volatile("" : "+v"(sq));   // block FMA contraction: np rounds x*x first
        r[j] = sq;
      }
    }
    for (int i = 8; i < 128; i += 8) {
      const float4 v0 = *(const float4*)(p + i);
      const float4 v1 = *(const float4*)(p + i + 4);
      const float xs[8] = {v0.x, v0.y, v0.z, v0.w, v1.x, v1.y, v1.z, v1.w};
#pragma unroll
      for (int j = 0; j < 8; ++j) {
        float sq = xs[j] * xs[j];
        asm volatile("" : "+v"(sq));
        r[j] = r[j] + sq;
      }
    }
    half_s[h] = ((r[0] + r[1]) + (r[2] + r[3])) + ((r[4] + r[5]) + (r[6] + r[7]));
  }
  *outp = half_s[0] + half_s[1];
}

// ---------------------------------------------------------------------------
// k_argmin v5 (UNCHANGED from round 6 — 867 µs, VALUBusy 68%, bit-exact):
// 256x128 block tile, 256 threads, 16x8 micro-tile, double-buffered LDS.
// Accumulation: sequential k, FMA — bit-identical to np's BLAS-order match.
// Cross-block reduce via atomicMin on packed (float_bits(d)<<32)|col.
// ---------------------------------------------------------------------------
__global__ __launch_bounds__(256)
__attribute__((amdgpu_waves_per_eu(2, 2)))
void k_argmin(
    const float* __restrict__ z, const float* __restrict__ emb,
    const float* __restrict__ zsq, const float* __restrict__ esq,
    u64* __restrict__ best)
{
  __shared__ float As[2][BK][TM];       // 32 KB
  __shared__ float Bs[2][BK][TN];       // 16 KB

  const int tid = threadIdx.x;
  const int tx = tid & 15;
  const int ty = tid >> 4;
  const int tx4 = tx * 4;
  const int ty4 = ty * 4;
  const int R0 = blockIdx.x * TM;
  const int C0 = blockIdx.y * CHW;

  const int bcol = tid & 127;           // B staging col
  const int bk8  = (tid >> 7) * 8;      // B staging k-offset (0 or 8)

  const float* zrow = z + (size_t)(R0 + tid) * DD;

  u64 bp[16];
#pragma unroll
  for (int i = 0; i < 16; ++i) bp[i] = ~0ull;

#define STAGE(B_, K_)                                                     \
  {                                                                       \
    _Pragma("unroll")                                                     \
    for (int q = 0; q < 4; ++q) {                                         \
      const float4 v = *(const float4*)(zrow + (K_) + 4 * q);             \
      As[B_][4 * q + 0][tid] = v.x;                                       \
      As[B_][4 * q + 1][tid] = v.y;                                       \
      As[B_][4 * q + 2][tid] = v.z;                                       \
      As[B_][4 * q + 3][tid] = v.w;                                       \
    }                                                                     \
    _Pragma("unroll")                                                     \
    for (int h = 0; h < 2; ++h) {                                         \
      const float4 v = *(const float4*)(ecol + (K_) + 4 * h);             \
      Bs[B_][bk8 + 4 * h + 0][bcol] = v.x;                                \
      Bs[B_][bk8 + 4 * h + 1][bcol] = v.y;                                \
      Bs[B_][bk8 + 4 * h + 2][bcol] = v.z;                                \
      Bs[B_][bk8 + 4 * h + 3][bcol] = v.w;                                \
    }                                                                     \
  }

#define COMPUTE(B_)                                                       \
  _Pragma("unroll 2")                                                     \
  for (int kk = 0; kk < BK; ++kk) {                                       \
    const float4 a0 = *(const float4*)(&As[B_][kk][ty4]);                 \
    const float4 a1 = *(const float4*)(&As[B_][kk][ty4 + 64]);            \
    const float4 a2 = *(const float4*)(&As[B_][kk][ty4 + 128]);           \
    const float4 a3 = *(const float4*)(&As[B_][kk][ty4 + 192]);           \
    const float4 b0 = *(const float4*)(&Bs[B_][kk][tx4]);                 \
    const float4 b1 = *(const float4*)(&Bs[B_][kk][tx4 + 64]);            \
    const float av[16] = {a0.x, a0.y, a0.z, a0.w, a1.x, a1.y, a1.z, a1.w, \
                          a2.x, a2.y, a2.z, a2.w, a3.x, a3.y, a3.z, a3.w};\
    const float bv[8]  = {b0.x, b0.y, b0.z, b0.w, b1.x, b1.y, b1.z, b1.w};\
    _Pragma("unroll")                                                     \
    for (int i = 0; i < 16; ++i)                                          \
      _Pragma("unroll")                                                   \
      for (int j = 0; j < 8; ++j)                                         \
        acc[i][j] += av[i] * bv[j];                                       \
  }

  for (int t = 0; t < CHW; t += TN) {
    const int Cb = C0 + t;
    const float* ecol = emb + (size_t)(Cb + bcol) * DD + bk8;

    float acc[16][8];
#pragma unroll
    for (int i = 0; i < 16; ++i)
#pragma unroll
      for (int j = 0; j < 8; ++j) acc[i][j] = 0.0f;

    STAGE(0, 0);
    __syncthreads();
    for (int c = 0; c < 16; c += 2) {
      if (c + 1 < 16) STAGE(1, (c + 1) * BK);
      COMPUTE(0);
      __syncthreads();
      if (c + 2 < 16) STAGE(0, (c + 2) * BK);
      COMPUTE(1);
      __syncthreads();
    }

#pragma unroll
    for (int j = 0; j < 8; ++j) {
      const int col = Cb + tx4 + ((j < 4) ? j : 64 + j - 4);
      const float ev = esq[col];
#pragma unroll
      for (int i = 0; i < 16; ++i) {
        const float zri = zsq[R0 + (i >> 2) * 64 + ty4 + (i & 3)];
        const float s1 = zri + ev;                // fl(zsq+esq), matches np
        const float dv = s1 - 2.0f * acc[i][j];   // fl(s1 - 2*dot); 2*dot exact
        const u64 p = ((u64)__float_as_uint(dv) << 32) | (unsigned)col;
        if (p < bp[i]) bp[i] = p;
      }
    }
  }

#pragma unroll
  for (int i = 0; i < 16; ++i) {
#pragma unroll
    for (int off = 8; off > 0; off >>= 1) {
      const u64 o = __shfl_xor(bp[i], off, 16);
      if (o < bp[i]) bp[i] = o;
    }
  }
  if (tx == 0) {
#pragma unroll
    for (int i = 0; i < 16; ++i) {
      const int r = R0 + (i >> 2) * 64 + ty4 + (i & 3);
      atomicMin(&best[r], bp[i]);
    }
  }
}

// ---------------------------------------------------------------------------
// k_emit2: ONE full pass over the 537 MB one-hot region writing zeros AND the
// 1.0s, with 16B-ALIGNED stores. The region base (out+4194306) is only
// 8B-aligned; the interior [base+2, end-2) is 16B-aligned. Each vf4 at flat
// onehot index f0=4t+2 lies in one row unless c=(f0&8191)==8190 (row cross).
// best[row] loads are wave-uniform (32 KB/row vs 1 KB/wave-step) -> L2 hit.
// ---------------------------------------------------------------------------
#define OH_TOT ((size_t)NROWS * NE)           // 134217728 floats
#define OH_VEC ((OH_TOT - 4) / 4)             // 33554431 aligned vf4 stores
__global__ __launch_bounds__(256) void k_emit2(
    const u64* __restrict__ best, float* __restrict__ base)
{
  const size_t i0 = (size_t)blockIdx.x * 256 + threadIdx.x;
  const size_t stride = (size_t)gridDim.x * 256;
  float* p = base + 2;                        // 16B-aligned

  for (size_t t = i0; t < OH_VEC; t += stride) {
    const size_t f0 = 4 * t + 2;
    const int row = (int)(f0 >> 13);
    const int c = (int)(f0 & 8191);
    const int idx = (int)(unsigned)(best[row] & 0xffffffffull);
    vf4 v;
    if (c <= 8188) {
      v.x = (c + 0 == idx) ? 1.0f : 0.0f;
      v.y = (c + 1 == idx) ? 1.0f : 0.0f;
      v.z = (c + 2 == idx) ? 1.0f : 0.0f;
      v.w = (c + 3 == idx) ? 1.0f : 0.0f;
    } else {  // c == 8190: cols 8190,8191 of row; cols 0,1 of row+1
      const int idx1 = (int)(unsigned)(best[row + 1] & 0xffffffffull);
      v.x = (8190 == idx) ? 1.0f : 0.0f;
      v.y = (8191 == idx) ? 1.0f : 0.0f;
      v.z = (0 == idx1) ? 1.0f : 0.0f;
      v.w = (1 == idx1) ? 1.0f : 0.0f;
    }
    *(vf4*)(p + 4 * t) = v;
  }

  if (i0 == 0) {
    const int idxA = (int)(unsigned)(best[0] & 0xffffffffull);
    base[0] = (idxA == 0) ? 1.0f : 0.0f;
    base[1] = (idxA == 1) ? 1.0f : 0.0f;
    const int idxZ = (int)(unsigned)(best[NROWS - 1] & 0xffffffffull);
    base[OH_TOT - 2] = (idxZ == 8190) ? 1.0f : 0.0f;
    base[OH_TOT - 1] = (idxZ == 8191) ? 1.0f : 0.0f;
  }
}

// ---------------------------------------------------------------------------
// k_gather2: 4 rows per block. z_q gather, float(index), counts, and loss
// partial per BLOCK (no single-address global atomic).
// ---------------------------------------------------------------------------
__global__ __launch_bounds__(256) void k_gather2(
    const float* __restrict__ z, const float* __restrict__ emb,
    const u64* __restrict__ best,
    float* __restrict__ out_zq, float* __restrict__ out_idx,
    float* __restrict__ partials, int* __restrict__ counts)
{
  __shared__ float sred[256];
  const int row = blockIdx.x * 4 + (threadIdx.x >> 6);
  const int lane = threadIdx.x & 63;
  const int idx = (int)(unsigned)(best[row] & 0xffffffffull);
  const int k0 = lane * 4;

  const float4 e  = *(const float4*)(emb + (size_t)idx * DD + k0);
  const float4 zv = *(const float4*)(z + (size_t)row * DD + k0);
  *(float4*)(out_zq + (size_t)row * DD + k0) = e;

  const float dx = e.x - zv.x, dy = e.y - zv.y, dz = e.z - zv.z, dw = e.w - zv.w;
  sred[threadIdx.x] = dx * dx + dy * dy + dz * dz + dw * dw;

  if (lane == 0) {
    out_idx[row] = (float)idx;
    atomicAdd(&counts[idx], 1);
  }
  __syncthreads();
  for (int s = 128; s > 0; s >>= 1) {
    if (threadIdx.x < s) sred[threadIdx.x] += sred[threadIdx.x + s];
    __syncthreads();
  }
  if (threadIdx.x == 0) partials[blockIdx.x] = sred[0];
}

// ---------------------------------------------------------------------------
// k_final: loss = 1.25 * sum(partials)/ (N*D); perplexity from counts.
// ---------------------------------------------------------------------------
__global__ __launch_bounds__(256) void k_final(
    const int* __restrict__ counts, const float* __restrict__ partials,
    float* __restrict__ out_loss, float* __restrict__ out_perp)
{
  __shared__ float sred[256];
  __shared__ float sl[256];
  float le = 0.0f;
  for (int e = threadIdx.x; e < NE; e += 256) {
    const float p = (float)counts[e] * (1.0f / 16384.0f);
    le += p * logf(p + 1e-10f);
  }
  float ll = 0.0f;
  for (int b = threadIdx.x; b < NROWS / 4; b += 256) ll += partials[b];
  sred[threadIdx.x] = le;
  sl[threadIdx.x] = ll;
  __syncthreads();
  for (int s = 128; s > 0; s >>= 1) {
    if (threadIdx.x < s) {
      sred[threadIdx.x] += sred[threadIdx.x + s];
      sl[threadIdx.x] += sl[threadIdx.x + s];
    }
    __syncthreads();
  }
  if (threadIdx.x == 0) {
    *out_perp = expf(-sred[0]);
    *out_loss = sl[0] * (1.25f / 4194304.0f);  // (1+beta) * sum / (N*D)
  }
}

// ---------------------------------------------------------------------------
// Output layout (float32, concatenated in reference return order):
//   [0]                loss                       (1)
//   [1 .. 4194304]     z_q_st                     (16384*256)
//   [4194305]          perplexity                 (1)
//   [4194306 ..]       min_encodings one-hot      (16384*8192)
//   [138412034 ..]     min_encoding_indices       (16384, written as float)
// ---------------------------------------------------------------------------
extern "C" void kernel_launch(void* const* d_in, const int* in_sizes, int n_in,
                              void* d_out, int out_size, void* d_ws, size_t ws_size,
                              hipStream_t stream) {
  const float* z   = (const float*)d_in[0];
  const float* emb = (const float*)d_in[1];

  float* out        = (float*)d_out;
  float* out_loss   = out;
  float* out_zq     = out + 1;
  float* out_perp   = out + 4194305;
  float* out_onehot = out + 4194306;
  float* out_idx    = out + 138412034;

  float* zsq      = (float*)d_ws;            // 16384 f
  float* esq      = zsq + NROWS;             // 8192 f
  u64*   best     = (u64*)(esq + NE);        // 16384 u64 (8B-aligned: offset 96 KB)
  int*   counts   = (int*)(best + NROWS);    // 8192 int
  float* partials = (float*)(counts + NE);   // 4096 f

  k_rowsq<<<96, 256, 0, stream>>>(z, emb, zsq, esq, best, counts);
  k_argmin<<<dim3(NROWS / TM, NCH), 256, 0, stream>>>(z, emb, zsq, esq, best);
  k_emit2<<<2048, 256, 0, stream>>>(best, out_onehot);
  k_gather2<<<NROWS / 4, 256, 0, stream>>>(z, emb, best, out_zq, out_idx,
                                           partials, counts);
  k_final<<<1, 256, 0, stream>>>(counts, partials, out_loss, out_perp);
}

// Round 8
// 1310.786 us; speedup vs baseline: 1.2769x; 1.0643x over previous
//
#include <hip/hip_runtime.h>
#include <cstddef>

#define NROWS 16384
#define NE    8192
#define DD    256
#define TM    256
#define TN    128
#define BK    16
#define NCH   8
#define CHW   (NE / NCH)   // 1024 cols per chunk

typedef unsigned long long u64;
typedef float vf4 __attribute__((ext_vector_type(4)));

#define OH_TOT ((size_t)NROWS * NE)           // 134217728 floats
#define OH_VEC ((OH_TOT - 4) / 4)             // 33554431 aligned vf4 slots

// ---------------------------------------------------------------------------
// k_rowsq: zsq[n] = sum(z[n,:]^2) in numpy pairwise order (256 = 128+128,
// each 128-block via 8 strided accumulators r[j] += x[8i+j]^2, combined
// pairwise). float4 loads (same add order as scalar). Also inits best[],
// counts.
// ---------------------------------------------------------------------------
__global__ __launch_bounds__(256) void k_rowsq(
    const float* __restrict__ z, const float* __restrict__ emb,
    float* __restrict__ zsq, float* __restrict__ esq,
    u64* __restrict__ best, int* __restrict__ counts)
{
  const int g = blockIdx.x * 256 + threadIdx.x;   // 0 .. 24575
  if (g < NE) counts[g] = 0;
  if (g < NROWS) best[g] = ~0ull;

  const float* row;
  float* outp;
  if (g < NROWS) { row = z + (size_t)g * DD;            outp = zsq + g; }
  else           { row = emb + (size_t)(g - NROWS) * DD; outp = esq + (g - NROWS); }

  float half_s[2];
#pragma unroll
  for (int h = 0; h < 2; ++h) {
    const float* p = row + h * 128;
    float r[8];
    {
      const float4 v0 = *(const float4*)(p);
      const float4 v1 = *(const float4*)(p + 4);
      const float xs[8] = {v0.x, v0.y, v0.z, v0.w, v1.x, v1.y, v1.z, v1.w};
#pragma unroll
      for (int j = 0; j < 8; ++j) {
        float sq = xs[j] * xs[j];
        asm volatile("" : "+v"(sq));   // block FMA contraction: np rounds x*x first
        r[j] = sq;
      }
    }
    for (int i = 8; i < 128; i += 8) {
      const float4 v0 = *(const float4*)(p + i);
      const float4 v1 = *(const float4*)(p + i + 4);
      const float xs[8] = {v0.x, v0.y, v0.z, v0.w, v1.x, v1.y, v1.z, v1.w};
#pragma unroll
      for (int j = 0; j < 8; ++j) {
        float sq = xs[j] * xs[j];
        asm volatile("" : "+v"(sq));
        r[j] = r[j] + sq;
      }
    }
    half_s[h] = ((r[0] + r[1]) + (r[2] + r[3])) + ((r[4] + r[5]) + (r[6] + r[7]));
  }
  *outp = half_s[0] + half_s[1];
}

// ---------------------------------------------------------------------------
// k_argmin v6: GEMM-argmin (unchanged numerics: sequential-k FMA, u64-packed
// atomicMin, bit-identical to rounds 1-7) + FUSED one-hot zero-fill.
// Round-7 counters: argmin hbm = 0.67% peak while the separate one-hot zero
// pass burned ~480 µs at ~1.2 TB/s. The zeros are best-independent, so each
// thread streams 256 nontemporal vf4 zero-stores (2 per STAGE, 128 STAGEs)
// into its block's private 1 MB span of the one-hot region — riding the idle
// memory pipe. The 1.0 positions are written later by k_gather2 (stream
// ordering guarantees zeros land first).
// ---------------------------------------------------------------------------
__global__ __launch_bounds__(256)
__attribute__((amdgpu_waves_per_eu(2, 2)))
void k_argmin(
    const float* __restrict__ z, const float* __restrict__ emb,
    const float* __restrict__ zsq, const float* __restrict__ esq,
    u64* __restrict__ best, float* __restrict__ ohbase)
{
  __shared__ float As[2][BK][TM];       // 32 KB
  __shared__ float Bs[2][BK][TN];       // 16 KB

  const int tid = threadIdx.x;
  const int tx = tid & 15;
  const int ty = tid >> 4;
  const int tx4 = tx * 4;
  const int ty4 = ty * 4;
  const int R0 = blockIdx.x * TM;
  const int C0 = blockIdx.y * CHW;

  const int bcol = tid & 127;           // B staging col
  const int bk8  = (tid >> 7) * 8;      // B staging k-offset (0 or 8)

  const float* zrow = z + (size_t)(R0 + tid) * DD;

  // one-hot zero-fill state: flat block id owns vf4 slots [b*65536,(b+1)*65536)
  const int bflat = blockIdx.y * (NROWS / TM) + blockIdx.x;   // 0..511
  size_t zt = (size_t)bflat * 65536 + tid;                    // step 256, x256
  float* zp = ohbase + 2;                                     // 16B-aligned
  const vf4 zzero = {0.0f, 0.0f, 0.0f, 0.0f};
  if (bflat == 0 && tid == 0) { ohbase[0] = 0.0f; ohbase[1] = 0.0f; }
  if (bflat == 511 && tid == 0) { ohbase[OH_TOT - 2] = 0.0f; ohbase[OH_TOT - 1] = 0.0f; }

  u64 bp[16];
#pragma unroll
  for (int i = 0; i < 16; ++i) bp[i] = ~0ull;

#define STAGE(B_, K_)                                                     \
  {                                                                       \
    _Pragma("unroll")                                                     \
    for (int q = 0; q < 4; ++q) {                                         \
      const float4 v = *(const float4*)(zrow + (K_) + 4 * q);             \
      As[B_][4 * q + 0][tid] = v.x;                                       \
      As[B_][4 * q + 1][tid] = v.y;                                       \
      As[B_][4 * q + 2][tid] = v.z;                                       \
      As[B_][4 * q + 3][tid] = v.w;                                       \
    }                                                                     \
    _Pragma("unroll")                                                     \
    for (int h = 0; h < 2; ++h) {                                         \
      const float4 v = *(const float4*)(ecol + (K_) + 4 * h);             \
      Bs[B_][bk8 + 4 * h + 0][bcol] = v.x;                                \
      Bs[B_][bk8 + 4 * h + 1][bcol] = v.y;                                \
      Bs[B_][bk8 + 4 * h + 2][bcol] = v.z;                                \
      Bs[B_][bk8 + 4 * h + 3][bcol] = v.w;                                \
    }                                                                     \
    if (zt < OH_VEC) __builtin_nontemporal_store(zzero, (vf4*)(zp + 4 * zt)); \
    zt += 256;                                                            \
    if (zt < OH_VEC) __builtin_nontemporal_store(zzero, (vf4*)(zp + 4 * zt)); \
    zt += 256;                                                            \
  }

#define COMPUTE(B_)                                                       \
  _Pragma("unroll 2")                                                     \
  for (int kk = 0; kk < BK; ++kk) {                                       \
    const float4 a0 = *(const float4*)(&As[B_][kk][ty4]);                 \
    const float4 a1 = *(const float4*)(&As[B_][kk][ty4 + 64]);            \
    const float4 a2 = *(const float4*)(&As[B_][kk][ty4 + 128]);           \
    const float4 a3 = *(const float4*)(&As[B_][kk][ty4 + 192]);           \
    const float4 b0 = *(const float4*)(&Bs[B_][kk][tx4]);                 \
    const float4 b1 = *(const float4*)(&Bs[B_][kk][tx4 + 64]);            \
    const float av[16] = {a0.x, a0.y, a0.z, a0.w, a1.x, a1.y, a1.z, a1.w, \
                          a2.x, a2.y, a2.z, a2.w, a3.x, a3.y, a3.z, a3.w};\
    const float bv[8]  = {b0.x, b0.y, b0.z, b0.w, b1.x, b1.y, b1.z, b1.w};\
    _Pragma("unroll")                                                     \
    for (int i = 0; i < 16; ++i)                                          \
      _Pragma("unroll")                                                   \
      for (int j = 0; j < 8; ++j)                                         \
        acc[i][j] += av[i] * bv[j];                                       \
  }

  for (int t = 0; t < CHW; t += TN) {
    const int Cb = C0 + t;
    const float* ecol = emb + (size_t)(Cb + bcol) * DD + bk8;

    float acc[16][8];
#pragma unroll
    for (int i = 0; i < 16; ++i)
#pragma unroll
      for (int j = 0; j < 8; ++j) acc[i][j] = 0.0f;

    STAGE(0, 0);
    __syncthreads();
    for (int c = 0; c < 16; c += 2) {
      if (c + 1 < 16) STAGE(1, (c + 1) * BK);
      COMPUTE(0);
      __syncthreads();
      if (c + 2 < 16) STAGE(0, (c + 2) * BK);
      COMPUTE(1);
      __syncthreads();
    }

#pragma unroll
    for (int j = 0; j < 8; ++j) {
      const int col = Cb + tx4 + ((j < 4) ? j : 64 + j - 4);
      const float ev = esq[col];
#pragma unroll
      for (int i = 0; i < 16; ++i) {
        const float zri = zsq[R0 + (i >> 2) * 64 + ty4 + (i & 3)];
        const float s1 = zri + ev;                // fl(zsq+esq), matches np
        const float dv = s1 - 2.0f * acc[i][j];   // fl(s1 - 2*dot); 2*dot exact
        const u64 p = ((u64)__float_as_uint(dv) << 32) | (unsigned)col;
        if (p < bp[i]) bp[i] = p;
      }
    }
  }

#pragma unroll
  for (int i = 0; i < 16; ++i) {
#pragma unroll
    for (int off = 8; off > 0; off >>= 1) {
      const u64 o = __shfl_xor(bp[i], off, 16);
      if (o < bp[i]) bp[i] = o;
    }
  }
  if (tx == 0) {
#pragma unroll
    for (int i = 0; i < 16; ++i) {
      const int r = R0 + (i >> 2) * 64 + ty4 + (i & 3);
      atomicMin(&best[r], bp[i]);
    }
  }
}

// ---------------------------------------------------------------------------
// k_gather2: 4 rows per block. z_q gather, one-hot 1.0 scatter (zeros were
// laid down by k_argmin), float(index), counts, per-block loss partial.
// ---------------------------------------------------------------------------
__global__ __launch_bounds__(256) void k_gather2(
    const float* __restrict__ z, const float* __restrict__ emb,
    const u64* __restrict__ best,
    float* __restrict__ out_zq, float* __restrict__ out_onehot,
    float* __restrict__ out_idx, float* __restrict__ partials,
    int* __restrict__ counts)
{
  __shared__ float sred[256];
  const int row = blockIdx.x * 4 + (threadIdx.x >> 6);
  const int lane = threadIdx.x & 63;
  const int idx = (int)(unsigned)(best[row] & 0xffffffffull);
  const int k0 = lane * 4;

  const float4 e  = *(const float4*)(emb + (size_t)idx * DD + k0);
  const float4 zv = *(const float4*)(z + (size_t)row * DD + k0);
  *(float4*)(out_zq + (size_t)row * DD + k0) = e;

  const float dx = e.x - zv.x, dy = e.y - zv.y, dz = e.z - zv.z, dw = e.w - zv.w;
  sred[threadIdx.x] = dx * dx + dy * dy + dz * dz + dw * dw;

  if (lane == 0) {
    out_idx[row] = (float)idx;
    out_onehot[(size_t)row * NE + idx] = 1.0f;
    atomicAdd(&counts[idx], 1);
  }
  __syncthreads();
  for (int s = 128; s > 0; s >>= 1) {
    if (threadIdx.x < s) sred[threadIdx.x] += sred[threadIdx.x + s];
    __syncthreads();
  }
  if (threadIdx.x == 0) partials[blockIdx.x] = sred[0];
}

// ---------------------------------------------------------------------------
// k_final: loss = 1.25 * sum(partials) / (N*D); perplexity from counts.
// ---------------------------------------------------------------------------
__global__ __launch_bounds__(256) void k_final(
    const int* __restrict__ counts, const float* __restrict__ partials,
    float* __restrict__ out_loss, float* __restrict__ out_perp)
{
  __shared__ float sred[256];
  __shared__ float sl[256];
  float le = 0.0f;
  for (int e = threadIdx.x; e < NE; e += 256) {
    const float p = (float)counts[e] * (1.0f / 16384.0f);
    le += p * logf(p + 1e-10f);
  }
  float ll = 0.0f;
  for (int b = threadIdx.x; b < NROWS / 4; b += 256) ll += partials[b];
  sred[threadIdx.x] = le;
  sl[threadIdx.x] = ll;
  __syncthreads();
  for (int s = 128; s > 0; s >>= 1) {
    if (threadIdx.x < s) {
      sred[threadIdx.x] += sred[threadIdx.x + s];
      sl[threadIdx.x] += sl[threadIdx.x + s];
    }
    __syncthreads();
  }
  if (threadIdx.x == 0) {
    *out_perp = expf(-sred[0]);
    *out_loss = sl[0] * (1.25f / 4194304.0f);  // (1+beta) * sum / (N*D)
  }
}

// ---------------------------------------------------------------------------
// Output layout (float32, concatenated in reference return order):
//   [0]                loss                       (1)
//   [1 .. 4194304]     z_q_st                     (16384*256)
//   [4194305]          perplexity                 (1)
//   [4194306 ..]       min_encodings one-hot      (16384*8192)
//   [138412034 ..]     min_encoding_indices       (16384, written as float)
// ---------------------------------------------------------------------------
extern "C" void kernel_launch(void* const* d_in, const int* in_sizes, int n_in,
                              void* d_out, int out_size, void* d_ws, size_t ws_size,
                              hipStream_t stream) {
  const float* z   = (const float*)d_in[0];
  const float* emb = (const float*)d_in[1];

  float* out        = (float*)d_out;
  float* out_loss   = out;
  float* out_zq     = out + 1;
  float* out_perp   = out + 4194305;
  float* out_onehot = out + 4194306;
  float* out_idx    = out + 138412034;

  float* zsq      = (float*)d_ws;            // 16384 f
  float* esq      = zsq + NROWS;             // 8192 f
  u64*   best     = (u64*)(esq + NE);        // 16384 u64 (8B-aligned: offset 96 KB)
  int*   counts   = (int*)(best + NROWS);    // 8192 int
  float* partials = (float*)(counts + NE);   // 4096 f

  k_rowsq<<<96, 256, 0, stream>>>(z, emb, zsq, esq, best, counts);
  k_argmin<<<dim3(NROWS / TM, NCH), 256, 0, stream>>>(z, emb, zsq, esq, best,
                                                      out_onehot);
  k_gather2<<<NROWS / 4, 256, 0, stream>>>(z, emb, best, out_zq, out_onehot,
                                           out_idx, partials, counts);
  k_final<<<1, 256, 0, stream>>>(counts, partials, out_loss, out_perp);
}

// Round 9
// 1302.061 us; speedup vs baseline: 1.2855x; 1.0067x over previous
//
#include <hip/hip_runtime.h>
#include <cstddef>

#define NROWS 16384
#define NE    8192
#define DD    256
#define TM    256
#define TN    128
#define BK    16
#define NCH   8
#define CHW   (NE / NCH)   // 1024 cols per chunk

typedef unsigned long long u64;
typedef float vf4 __attribute__((ext_vector_type(4)));
typedef float vf2 __attribute__((ext_vector_type(2)));

#define OH_TOT ((size_t)NROWS * NE)           // 134217728 floats
#define OH_VEC ((OH_TOT - 4) / 4)             // 33554431 aligned vf4 slots

// ---------------------------------------------------------------------------
// k_rowsq: zsq[n] = sum(z[n,:]^2) in numpy pairwise order (256 = 128+128,
// each 128-block via 8 strided accumulators r[j] += x[8i+j]^2, combined
// pairwise). float4 loads (same add order as scalar). Also inits best[],
// counts.
// ---------------------------------------------------------------------------
__global__ __launch_bounds__(256) void k_rowsq(
    const float* __restrict__ z, const float* __restrict__ emb,
    float* __restrict__ zsq, float* __restrict__ esq,
    u64* __restrict__ best, int* __restrict__ counts)
{
  const int g = blockIdx.x * 256 + threadIdx.x;   // 0 .. 24575
  if (g < NE) counts[g] = 0;
  if (g < NROWS) best[g] = ~0ull;

  const float* row;
  float* outp;
  if (g < NROWS) { row = z + (size_t)g * DD;            outp = zsq + g; }
  else           { row = emb + (size_t)(g - NROWS) * DD; outp = esq + (g - NROWS); }

  float half_s[2];
#pragma unroll
  for (int h = 0; h < 2; ++h) {
    const float* p = row + h * 128;
    float r[8];
    {
      const float4 v0 = *(const float4*)(p);
      const float4 v1 = *(const float4*)(p + 4);
      const float xs[8] = {v0.x, v0.y, v0.z, v0.w, v1.x, v1.y, v1.z, v1.w};
#pragma unroll
      for (int j = 0; j < 8; ++j) {
        float sq = xs[j] * xs[j];
        asm volatile("" : "+v"(sq));   // block FMA contraction: np rounds x*x first
        r[j] = sq;
      }
    }
    for (int i = 8; i < 128; i += 8) {
      const float4 v0 = *(const float4*)(p + i);
      const float4 v1 = *(const float4*)(p + i + 4);
      const float xs[8] = {v0.x, v0.y, v0.z, v0.w, v1.x, v1.y, v1.z, v1.w};
#pragma unroll
      for (int j = 0; j < 8; ++j) {
        float sq = xs[j] * xs[j];
        asm volatile("" : "+v"(sq));
        r[j] = r[j] + sq;
      }
    }
    half_s[h] = ((r[0] + r[1]) + (r[2] + r[3])) + ((r[4] + r[5]) + (r[6] + r[7]));
  }
  *outp = half_s[0] + half_s[1];
}

// ---------------------------------------------------------------------------
// k_argmin v7: identical to v6 (fused one-hot zero-fill, double-buffered LDS,
// u64-packed atomicMin argmin) except the inner product now uses
// v_pk_fma_f32 via vf2 accumulators + __builtin_elementwise_fma: one VOP3P
// instruction = 2 IEEE-fused fp32 FMAs per lane. Each half rounds exactly
// like v_fma_f32, and the per-(row,col) accumulation sequence (ascending k)
// is unchanged -> argmin decisions bit-identical to rounds 1-8.
// ---------------------------------------------------------------------------
__global__ __launch_bounds__(256)
__attribute__((amdgpu_waves_per_eu(2, 2)))
void k_argmin(
    const float* __restrict__ z, const float* __restrict__ emb,
    const float* __restrict__ zsq, const float* __restrict__ esq,
    u64* __restrict__ best, float* __restrict__ ohbase)
{
  __shared__ float As[2][BK][TM];       // 32 KB
  __shared__ float Bs[2][BK][TN];       // 16 KB

  const int tid = threadIdx.x;
  const int tx = tid & 15;
  const int ty = tid >> 4;
  const int tx4 = tx * 4;
  const int ty4 = ty * 4;
  const int R0 = blockIdx.x * TM;
  const int C0 = blockIdx.y * CHW;

  const int bcol = tid & 127;           // B staging col
  const int bk8  = (tid >> 7) * 8;      // B staging k-offset (0 or 8)

  const float* zrow = z + (size_t)(R0 + tid) * DD;

  // one-hot zero-fill state: flat block id owns vf4 slots [b*65536,(b+1)*65536)
  const int bflat = blockIdx.y * (NROWS / TM) + blockIdx.x;   // 0..511
  size_t zt = (size_t)bflat * 65536 + tid;                    // step 256, x256
  float* zp = ohbase + 2;                                     // 16B-aligned
  const vf4 zzero = {0.0f, 0.0f, 0.0f, 0.0f};
  if (bflat == 0 && tid == 0) { ohbase[0] = 0.0f; ohbase[1] = 0.0f; }
  if (bflat == 511 && tid == 0) { ohbase[OH_TOT - 2] = 0.0f; ohbase[OH_TOT - 1] = 0.0f; }

  u64 bp[16];
#pragma unroll
  for (int i = 0; i < 16; ++i) bp[i] = ~0ull;

#define STAGE(B_, K_)                                                     \
  {                                                                       \
    _Pragma("unroll")                                                     \
    for (int q = 0; q < 4; ++q) {                                         \
      const float4 v = *(const float4*)(zrow + (K_) + 4 * q);             \
      As[B_][4 * q + 0][tid] = v.x;                                       \
      As[B_][4 * q + 1][tid] = v.y;                                       \
      As[B_][4 * q + 2][tid] = v.z;                                       \
      As[B_][4 * q + 3][tid] = v.w;                                       \
    }                                                                     \
    _Pragma("unroll")                                                     \
    for (int h = 0; h < 2; ++h) {                                         \
      const float4 v = *(const float4*)(ecol + (K_) + 4 * h);             \
      Bs[B_][bk8 + 4 * h + 0][bcol] = v.x;                                \
      Bs[B_][bk8 + 4 * h + 1][bcol] = v.y;                                \
      Bs[B_][bk8 + 4 * h + 2][bcol] = v.z;                                \
      Bs[B_][bk8 + 4 * h + 3][bcol] = v.w;                                \
    }                                                                     \
    if (zt < OH_VEC) __builtin_nontemporal_store(zzero, (vf4*)(zp + 4 * zt)); \
    zt += 256;                                                            \
    if (zt < OH_VEC) __builtin_nontemporal_store(zzero, (vf4*)(zp + 4 * zt)); \
    zt += 256;                                                            \
  }

#define COMPUTE(B_)                                                       \
  _Pragma("unroll 2")                                                     \
  for (int kk = 0; kk < BK; ++kk) {                                       \
    const float4 a0 = *(const float4*)(&As[B_][kk][ty4]);                 \
    const float4 a1 = *(const float4*)(&As[B_][kk][ty4 + 64]);            \
    const float4 a2 = *(const float4*)(&As[B_][kk][ty4 + 128]);           \
    const float4 a3 = *(const float4*)(&As[B_][kk][ty4 + 192]);           \
    const float4 b0 = *(const float4*)(&Bs[B_][kk][tx4]);                 \
    const float4 b1 = *(const float4*)(&Bs[B_][kk][tx4 + 64]);            \
    const float av[16] = {a0.x, a0.y, a0.z, a0.w, a1.x, a1.y, a1.z, a1.w, \
                          a2.x, a2.y, a2.z, a2.w, a3.x, a3.y, a3.z, a3.w};\
    const vf2 b2[4] = {{b0.x, b0.y}, {b0.z, b0.w},                        \
                       {b1.x, b1.y}, {b1.z, b1.w}};                       \
    _Pragma("unroll")                                                     \
    for (int i = 0; i < 16; ++i) {                                        \
      const vf2 a2v = {av[i], av[i]};                                     \
      _Pragma("unroll")                                                   \
      for (int j = 0; j < 4; ++j)                                         \
        acc[i][j] = __builtin_elementwise_fma(a2v, b2[j], acc[i][j]);     \
    }                                                                     \
  }

  for (int t = 0; t < CHW; t += TN) {
    const int Cb = C0 + t;
    const float* ecol = emb + (size_t)(Cb + bcol) * DD + bk8;

    vf2 acc[16][4];   // [i][j2]: j2=0,1 -> cols tx4+0..3 ; j2=2,3 -> tx4+64..67
#pragma unroll
    for (int i = 0; i < 16; ++i)
#pragma unroll
      for (int j = 0; j < 4; ++j) acc[i][j] = (vf2){0.0f, 0.0f};

    STAGE(0, 0);
    __syncthreads();
    for (int c = 0; c < 16; c += 2) {
      if (c + 1 < 16) STAGE(1, (c + 1) * BK);
      COMPUTE(0);
      __syncthreads();
      if (c + 2 < 16) STAGE(0, (c + 2) * BK);
      COMPUTE(1);
      __syncthreads();
    }

#pragma unroll
    for (int j = 0; j < 8; ++j) {
      const int col = Cb + tx4 + ((j < 4) ? j : 64 + j - 4);
      const float ev = esq[col];
#pragma unroll
      for (int i = 0; i < 16; ++i) {
        const float zri = zsq[R0 + (i >> 2) * 64 + ty4 + (i & 3)];
        const float aij = acc[i][j >> 1][j & 1];
        const float s1 = zri + ev;                // fl(zsq+esq), matches np
        const float dv = s1 - 2.0f * aij;         // fl(s1 - 2*dot); 2*dot exact
        const u64 p = ((u64)__float_as_uint(dv) << 32) | (unsigned)col;
        if (p < bp[i]) bp[i] = p;
      }
    }
  }

#pragma unroll
  for (int i = 0; i < 16; ++i) {
#pragma unroll
    for (int off = 8; off > 0; off >>= 1) {
      const u64 o = __shfl_xor(bp[i], off, 16);
      if (o < bp[i]) bp[i] = o;
    }
  }
  if (tx == 0) {
#pragma unroll
    for (int i = 0; i < 16; ++i) {
      const int r = R0 + (i >> 2) * 64 + ty4 + (i & 3);
      atomicMin(&best[r], bp[i]);
    }
  }
}

// ---------------------------------------------------------------------------
// k_gather2: 4 rows per block. z_q gather, one-hot 1.0 scatter (zeros were
// laid down by k_argmin), float(index), counts, per-block loss partial.
// ---------------------------------------------------------------------------
__global__ __launch_bounds__(256) void k_gather2(
    const float* __restrict__ z, const float* __restrict__ emb,
    const u64* __restrict__ best,
    float* __restrict__ out_zq, float* __restrict__ out_onehot,
    float* __restrict__ out_idx, float* __restrict__ partials,
    int* __restrict__ counts)
{
  __shared__ float sred[256];
  const int row = blockIdx.x * 4 + (threadIdx.x >> 6);
  const int lane = threadIdx.x & 63;
  const int idx = (int)(unsigned)(best[row] & 0xffffffffull);
  const int k0 = lane * 4;

  const float4 e  = *(const float4*)(emb + (size_t)idx * DD + k0);
  const float4 zv = *(const float4*)(z + (size_t)row * DD + k0);
  *(float4*)(out_zq + (size_t)row * DD + k0) = e;

  const float dx = e.x - zv.x, dy = e.y - zv.y, dz = e.z - zv.z, dw = e.w - zv.w;
  sred[threadIdx.x] = dx * dx + dy * dy + dz * dz + dw * dw;

  if (lane == 0) {
    out_idx[row] = (float)idx;
    out_onehot[(size_t)row * NE + idx] = 1.0f;
    atomicAdd(&counts[idx], 1);
  }
  __syncthreads();
  for (int s = 128; s > 0; s >>= 1) {
    if (threadIdx.x < s) sred[threadIdx.x] += sred[threadIdx.x + s];
    __syncthreads();
  }
  if (threadIdx.x == 0) partials[blockIdx.x] = sred[0];
}

// ---------------------------------------------------------------------------
// k_final: loss = 1.25 * sum(partials) / (N*D); perplexity from counts.
// ---------------------------------------------------------------------------
__global__ __launch_bounds__(256) void k_final(
    const int* __restrict__ counts, const float* __restrict__ partials,
    float* __restrict__ out_loss, float* __restrict__ out_perp)
{
  __shared__ float sred[256];
  __shared__ float sl[256];
  float le = 0.0f;
  for (int e = threadIdx.x; e < NE; e += 256) {
    const float p = (float)counts[e] * (1.0f / 16384.0f);
    le += p * logf(p + 1e-10f);
  }
  float ll = 0.0f;
  for (int b = threadIdx.x; b < NROWS / 4; b += 256) ll += partials[b];
  sred[threadIdx.x] = le;
  sl[threadIdx.x] = ll;
  __syncthreads();
  for (int s = 128; s > 0; s >>= 1) {
    if (threadIdx.x < s) {
      sred[threadIdx.x] += sred[threadIdx.x + s];
      sl[threadIdx.x] += sl[threadIdx.x + s];
    }
    __syncthreads();
  }
  if (threadIdx.x == 0) {
    *out_perp = expf(-sred[0]);
    *out_loss = sl[0] * (1.25f / 4194304.0f);  // (1+beta) * sum / (N*D)
  }
}

// ---------------------------------------------------------------------------
// Output layout (float32, concatenated in reference return order):
//   [0]                loss                       (1)
//   [1 .. 4194304]     z_q_st                     (16384*256)
//   [4194305]          perplexity                 (1)
//   [4194306 ..]       min_encodings one-hot      (16384*8192)
//   [138412034 ..]     min_encoding_indices       (16384, written as float)
// ---------------------------------------------------------------------------
extern "C" void kernel_launch(void* const* d_in, const int* in_sizes, int n_in,
                              void* d_out, int out_size, void* d_ws, size_t ws_size,
                              hipStream_t stream) {
  const float* z   = (const float*)d_in[0];
  const float* emb = (const float*)d_in[1];

  float* out        = (float*)d_out;
  float* out_loss   = out;
  float* out_zq     = out + 1;
  float* out_perp   = out + 4194305;
  float* out_onehot = out + 4194306;
  float* out_idx    = out + 138412034;

  float* zsq      = (float*)d_ws;            // 16384 f
  float* esq      = zsq + NROWS;             // 8192 f
  u64*   best     = (u64*)(esq + NE);        // 16384 u64 (8B-aligned: offset 96 KB)
  int*   counts   = (int*)(best + NROWS);    // 8192 int
  float* partials = (float*)(counts + NE);   // 4096 f

  k_rowsq<<<96, 256, 0, stream>>>(z, emb, zsq, esq, best, counts);
  k_argmin<<<dim3(NROWS / TM, NCH), 256, 0, stream>>>(z, emb, zsq, esq, best,
                                                      out_onehot);
  k_gather2<<<NROWS / 4, 256, 0, stream>>>(z, emb, best, out_zq, out_onehot,
                                           out_idx, partials, counts);
  k_final<<<1, 256, 0, stream>>>(counts, partials, out_loss, out_perp);
}